// Round 2
// baseline (494.286 us; speedup 1.0000x reference)
//
#include <hip/hip_runtime.h>
#include <math.h>

// Problem constants (match reference)
#define Bb   16
#define Cc   3
#define Hh   64
#define Ww   64
#define Kk   32
#define Ss   32
#define OHh  60
#define OWw  60
#define Pp   3600
#define XROW 65            // padded LDS row stride: lane-stride-65 floats -> bank stride 1
#define XCH  (64 * XROW)   // floats per channel in LDS = 4160
#define NGRP 900           // 60 rows * 15 groups of 4 columns
#define TPB  512

// coef layout: x=c0, y=dA(=c2-c0), z=dB(=c1-c0), w=dAB(=c0-c1-c2+c3)
// combine: y = c0 + a*dA + b*dB + a*b*dAB
__device__ __forceinline__ float4 combine4(const float4 a, const float4 b, const float4 c) {
    float4 r;
    r.x = fmaf(a.x, fmaf(b.x, c.w, c.y), fmaf(b.x, c.z, c.x));
    r.y = fmaf(a.y, fmaf(b.y, c.w, c.y), fmaf(b.y, c.z, c.x));
    r.z = fmaf(a.z, fmaf(b.z, c.w, c.y), fmaf(b.z, c.z, c.x));
    r.w = fmaf(a.w, fmaf(b.w, c.w, c.y), fmaf(b.w, c.z, c.x));
    return r;
}

// DFS tree evaluation via macros: NO arrays, only named scalars (no scratch).
// LEAF(n): level-0 node n (combines gather pair n with coefs[n])
#define LEAF(n, dst)                                                         \
    {                                                                        \
        const int2 bn = bases[(n)];                                          \
        const float* pa = &xs[bn.x + off];                                   \
        const float* pb = &xs[bn.y + off];                                   \
        const float4 av = make_float4(pa[0], pa[1], pa[2], pa[3]);           \
        const float4 bv = make_float4(pb[0], pb[1], pb[2], pb[3]);           \
        dst = combine4(av, bv, coefs[(n)]);                                  \
    }

#define SUB2(n, dst)  { float4 a0, b0; LEAF(2*(n), a0);  LEAF(2*(n)+1, b0);  dst = combine4(a0, b0, coefs[32 + (n)]); }
#define SUB4(n, dst)  { float4 a1, b1; SUB2(2*(n), a1);  SUB2(2*(n)+1, b1);  dst = combine4(a1, b1, coefs[48 + (n)]); }
#define SUB8(n, dst)  { float4 a2, b2; SUB4(2*(n), a2);  SUB4(2*(n)+1, b2);  dst = combine4(a2, b2, coefs[56 + (n)]); }
#define SUB16(n, dst) { float4 a3, b3; SUB8(2*(n), a3);  SUB8(2*(n)+1, b3);  dst = combine4(a3, b3, coefs[60 + (n)]); }

__global__ __launch_bounds__(TPB, 2) void logic_conv_kernel(
    const float* __restrict__ x,
    const int*   __restrict__ h_idx,
    const int*   __restrict__ w_idx,
    const int*   __restrict__ c_idx,
    const float* __restrict__ w0, const float* __restrict__ w1,
    const float* __restrict__ w2, const float* __restrict__ w3,
    const float* __restrict__ w4, const float* __restrict__ w5,
    float* __restrict__ out)
{
    __shared__ float  xs[Cc * XCH];     // 3*4160*4 = 49,920 B
    __shared__ float4 coefs[63];
    __shared__ int2   bases[32];

    const int tid = threadIdx.x;
    const int blk = blockIdx.x;
    const int b   = blk >> 5;           // / K
    const int k   = blk & 31;           // % K

    // ---- stage x[b] into padded LDS (12288 floats, float4 global reads) ----
    const float* xb = x + b * (Cc * Hh * Ww);
    #pragma unroll
    for (int it = 0; it < 6; ++it) {
        const int f = (it * TPB + tid) * 4;           // flat index, 16B-aligned
        const float4 v = *reinterpret_cast<const float4*>(xb + f);
        const int c   = f >> 12;                      // / 4096
        const int rem = f & 4095;
        const int h   = rem >> 6;
        const int w   = rem & 63;
        float* d = &xs[c * XCH + h * XROW + w];
        d[0] = v.x; d[1] = v.y; d[2] = v.z; d[3] = v.w;
    }

    // ---- gather bases: LDS offsets for each leaf's two inputs ----
    if (tid < 32) {
        const int i0 = (0 * Kk + k) * Ss + tid;
        const int i1 = (1 * Kk + k) * Ss + tid;
        bases[tid] = make_int2(
            c_idx[i0] * XCH + h_idx[i0] * XROW + w_idx[i0],
            c_idx[i1] * XCH + h_idx[i1] * XROW + w_idx[i1]);
    }

    // ---- per-node coefficients: softmax(w)/LUT folded to 4 floats ----
    if (tid >= 64 && tid < 127) {
        const int t = tid - 64;
        const float* wp; int n;
        if      (t < 32) { wp = w0; n = t;      }
        else if (t < 48) { wp = w1; n = t - 32; }
        else if (t < 56) { wp = w2; n = t - 48; }
        else if (t < 60) { wp = w3; n = t - 56; }
        else if (t < 62) { wp = w4; n = t - 60; }
        else             { wp = w5; n = 0;      }
        const float* lg = wp + (n * Kk + k) * 16;
        float l[16];
        float m = lg[0];
        #pragma unroll
        for (int q = 0; q < 16; ++q) { l[q] = lg[q]; m = fmaxf(m, l[q]); }
        float e[16], s = 0.f;
        #pragma unroll
        for (int q = 0; q < 16; ++q) { e[q] = __expf(l[q] - m); s += e[q]; }
        const float inv = 1.f / s;
        float c0 = 0.f, c1 = 0.f, c2 = 0.f, c3 = 0.f;
        #pragma unroll
        for (int op = 0; op < 16; ++op) {
            if (op & 1) c0 += e[op];
            if (op & 2) c1 += e[op];
            if (op & 4) c2 += e[op];
            if (op & 8) c3 += e[op];
        }
        c0 *= inv; c1 *= inv; c2 *= inv; c3 *= inv;
        coefs[t] = make_float4(c0, c2 - c0, c1 - c0, c0 - c1 - c2 + c3);
    }

    __syncthreads();

    // ---- main loop: oh-major mapping so lanes read LDS at stride XROW=65 ----
    float* outp = out + blk * Pp;
    for (int g = tid; g < NGRP; g += TPB) {
        const int oh  = g % 60;              // consecutive lanes -> consecutive rows
        const int ow0 = (g / 60) * 4;
        const int off = oh * XROW + ow0;

        float4 y;
        { float4 a4, b4; SUB16(0, a4); SUB16(1, b4); y = combine4(a4, b4, coefs[62]); }

        *reinterpret_cast<float4*>(outp + oh * OWw + ow0) = y;
    }
}

extern "C" void kernel_launch(void* const* d_in, const int* in_sizes, int n_in,
                              void* d_out, int out_size, void* d_ws, size_t ws_size,
                              hipStream_t stream) {
    const float* x     = (const float*)d_in[0];
    const int*   h_idx = (const int*)d_in[1];
    const int*   w_idx = (const int*)d_in[2];
    const int*   c_idx = (const int*)d_in[3];
    const float* w0    = (const float*)d_in[4];
    const float* w1    = (const float*)d_in[5];
    const float* w2    = (const float*)d_in[6];
    const float* w3    = (const float*)d_in[7];
    const float* w4    = (const float*)d_in[8];
    const float* w5    = (const float*)d_in[9];
    float* out = (float*)d_out;

    dim3 grid(Bb * Kk);   // 512 blocks: one per (b, k)
    dim3 block(TPB);
    hipLaunchKernelGGL(logic_conv_kernel, grid, block, 0, stream,
                       x, h_idx, w_idx, c_idx, w0, w1, w2, w3, w4, w5, out);
}

// Round 3
// 27.403 us; speedup vs baseline: 18.0376x; 18.0376x over previous
//
#include <hip/hip_runtime.h>
#include <math.h>

// Problem constants (match reference)
#define Bb   16
#define Cc   3
#define Hh   64
#define Ww   64
#define Kk   32
#define Ss   32
#define OHh  60
#define OWw  60
#define Pp   3600
#define XROW 65            // padded LDS row stride: lane row-stride -> bank stride 1
#define ROWS 34            // staged rows per block: 30 output rows + R-1
#define XCH  (ROWS * XROW) // 2210 floats per channel
#define OHSUB 30
#define NGRP 450           // 30 rows * 15 groups of 4 columns
#define TPB  256

// coef layout: x=c0, y=dA(=c2-c0), z=dB(=c1-c0), w=dAB(=c0-c1-c2+c3)
// combine: y = c0 + a*dA + b*dB + a*b*dAB
__device__ __forceinline__ float4 combine4(const float4 a, const float4 b, const float4 c) {
    float4 r;
    r.x = fmaf(a.x, fmaf(b.x, c.w, c.y), fmaf(b.x, c.z, c.x));
    r.y = fmaf(a.y, fmaf(b.y, c.w, c.y), fmaf(b.y, c.z, c.x));
    r.z = fmaf(a.z, fmaf(b.z, c.w, c.y), fmaf(b.z, c.z, c.x));
    r.w = fmaf(a.w, fmaf(b.w, c.w, c.y), fmaf(b.w, c.z, c.x));
    return r;
}

#define SB __builtin_amdgcn_sched_barrier(0)

// DFS tree evaluation via macros: named scalars only (no runtime-indexed arrays).
#define LEAF(n, dst)                                                         \
    {                                                                        \
        const int2 bn = bases[(n)];                                          \
        const float* pa = &xs[bn.x + off];                                   \
        const float* pb = &xs[bn.y + off];                                   \
        const float4 av = make_float4(pa[0], pa[1], pa[2], pa[3]);           \
        const float4 bv = make_float4(pb[0], pb[1], pb[2], pb[3]);           \
        dst = combine4(av, bv, coefs[(n)]);                                  \
    }

#define SUB2(n, dst)  { float4 a0, b0; LEAF(2*(n), a0);  LEAF(2*(n)+1, b0);  dst = combine4(a0, b0, coefs[32 + (n)]); }
#define SUB4(n, dst)  { float4 a1, b1; SUB2(2*(n), a1);  SUB2(2*(n)+1, b1);  dst = combine4(a1, b1, coefs[48 + (n)]); }
#define SUB8(n, dst)  { float4 a2, b2; SUB4(2*(n), a2);  SUB4(2*(n)+1, b2);  dst = combine4(a2, b2, coefs[56 + (n)]); }

__global__ __launch_bounds__(TPB) void logic_conv_kernel(
    const float* __restrict__ x,
    const int*   __restrict__ h_idx,
    const int*   __restrict__ w_idx,
    const int*   __restrict__ c_idx,
    const float* __restrict__ w0, const float* __restrict__ w1,
    const float* __restrict__ w2, const float* __restrict__ w3,
    const float* __restrict__ w4, const float* __restrict__ w5,
    float* __restrict__ out)
{
    __shared__ float  xs[Cc * XCH];     // 3*2210*4 = 26,520 B
    __shared__ float4 coefs[63];
    __shared__ int2   bases[32];

    const int tid  = threadIdx.x;
    const int blk  = blockIdx.x;
    const int b    = blk >> 6;          // 16 images
    const int k    = (blk >> 1) & 31;   // 32 filters
    const int half = blk & 1;           // row-half of the output
    const int oh0  = half * OHSUB;

    // ---- stage rows [oh0, oh0+34) of x[b] into padded LDS ----
    const float* xb = x + b * (Cc * Hh * Ww);
    #pragma unroll
    for (int it = 0; it < 7; ++it) {
        const int flat = it * TPB + tid;           // float4 index, 0..1631
        if (flat < Cc * ROWS * 16) {
            const int c   = flat / (ROWS * 16);    // /544
            const int rem = flat - c * (ROWS * 16);
            const int r   = rem >> 4;
            const int w4  = rem & 15;
            const float4 v = *reinterpret_cast<const float4*>(
                xb + c * (Hh * Ww) + (oh0 + r) * Ww + (w4 << 2));
            float* d = &xs[c * XCH + r * XROW + (w4 << 2)];
            d[0] = v.x; d[1] = v.y; d[2] = v.z; d[3] = v.w;
        }
    }

    // ---- gather bases: LDS offsets for each leaf's two inputs ----
    if (tid < 32) {
        const int i0 = (0 * Kk + k) * Ss + tid;
        const int i1 = (1 * Kk + k) * Ss + tid;
        bases[tid] = make_int2(
            c_idx[i0] * XCH + h_idx[i0] * XROW + w_idx[i0],
            c_idx[i1] * XCH + h_idx[i1] * XROW + w_idx[i1]);
    }

    // ---- per-node coefficients: softmax(w)/LUT folded to 4 floats ----
    if (tid >= 64 && tid < 127) {
        const int t = tid - 64;
        const float* wp; int n;
        if      (t < 32) { wp = w0; n = t;      }
        else if (t < 48) { wp = w1; n = t - 32; }
        else if (t < 56) { wp = w2; n = t - 48; }
        else if (t < 60) { wp = w3; n = t - 56; }
        else if (t < 62) { wp = w4; n = t - 60; }
        else             { wp = w5; n = 0;      }
        const float* lg = wp + (n * Kk + k) * 16;
        float l[16];
        float m = lg[0];
        #pragma unroll
        for (int q = 0; q < 16; ++q) { l[q] = lg[q]; m = fmaxf(m, l[q]); }
        float e[16], s = 0.f;
        #pragma unroll
        for (int q = 0; q < 16; ++q) { e[q] = __expf(l[q] - m); s += e[q]; }
        const float inv = 1.f / s;
        float c0 = 0.f, c1 = 0.f, c2 = 0.f, c3 = 0.f;
        #pragma unroll
        for (int op = 0; op < 16; ++op) {
            if (op & 1) c0 += e[op];
            if (op & 2) c1 += e[op];
            if (op & 4) c2 += e[op];
            if (op & 8) c3 += e[op];
        }
        c0 *= inv; c1 *= inv; c2 *= inv; c3 *= inv;
        coefs[t] = make_float4(c0, c2 - c0, c1 - c0, c0 - c1 - c2 + c3);
    }

    __syncthreads();

    // ---- main loop: oh-major (lane row-stride 1 -> conflict-free LDS reads) ----
    float* outp = out + (b * Kk + k) * Pp + oh0 * OWw;
    #pragma unroll 1
    for (int it = 0; it < 2; ++it) {
        const int g = it * TPB + tid;
        if (g < NGRP) {
            const int oh  = g % OHSUB;          // consecutive lanes -> consecutive rows
            const int ow0 = (g / OHSUB) << 2;
            const int off = oh * XROW + ow0;

            float4 s0, s1, s2, s3;
            SUB8(0, s0); SB;
            SUB8(1, s1); SB;
            SUB8(2, s2); SB;
            SUB8(3, s3); SB;
            const float4 t0 = combine4(s0, s1, coefs[60]);
            const float4 t1 = combine4(s2, s3, coefs[61]);
            const float4 y  = combine4(t0, t1, coefs[62]);

            *reinterpret_cast<float4*>(outp + oh * OWw + ow0) = y;
        }
    }
}

extern "C" void kernel_launch(void* const* d_in, const int* in_sizes, int n_in,
                              void* d_out, int out_size, void* d_ws, size_t ws_size,
                              hipStream_t stream) {
    const float* x     = (const float*)d_in[0];
    const int*   h_idx = (const int*)d_in[1];
    const int*   w_idx = (const int*)d_in[2];
    const int*   c_idx = (const int*)d_in[3];
    const float* w0    = (const float*)d_in[4];
    const float* w1    = (const float*)d_in[5];
    const float* w2    = (const float*)d_in[6];
    const float* w3    = (const float*)d_in[7];
    const float* w4    = (const float*)d_in[8];
    const float* w5    = (const float*)d_in[9];
    float* out = (float*)d_out;

    dim3 grid(Bb * Kk * 2);   // 1024 blocks: (b, k, row-half)
    dim3 block(TPB);
    hipLaunchKernelGGL(logic_conv_kernel, grid, block, 0, stream,
                       x, h_idx, w_idx, c_idx, w0, w1, w2, w3, w4, w5, out);
}

// Round 4
// 27.190 us; speedup vs baseline: 18.1788x; 1.0078x over previous
//
#include <hip/hip_runtime.h>
#include <math.h>

// Problem constants (match reference)
#define Bb   16
#define Cc   3
#define Hh   64
#define Ww   64
#define Kk   32
#define Ss   32
#define OHh  60
#define OWw  60
#define Pp   3600
#define XROW 65            // padded LDS row stride: lane row-stride -> bank stride 1
#define ROWS 34            // staged rows per block: 30 output rows + R-1
#define XCH  (ROWS * XROW) // 2210 floats per channel
#define OHSUB 30
#define NGRP 450           // 30 rows * 15 groups of 4 columns
#define TPB  256

typedef float vf4 __attribute__((ext_vector_type(4)));

#define SB __builtin_amdgcn_sched_barrier(0)

static __device__ __forceinline__ vf4 vsplat(float s) { return (vf4){s, s, s, s}; }

// combine: y = c0 + a*dA + b*dB + a*b*dAB  (c = {c0, dA, dB, dAB})
//        = fma(a, fma(b, dAB, dA), fma(b, dB, c0))  -> packed v_pk_fma_f32
static __device__ __forceinline__ vf4 comb(vf4 a, vf4 b, vf4 c) {
    const vf4 t = __builtin_elementwise_fma(b, vsplat(c.w), vsplat(c.y));
    const vf4 u = __builtin_elementwise_fma(b, vsplat(c.z), vsplat(c.x));
    return __builtin_elementwise_fma(a, t, u);
}

#define LD4(p) ((vf4){(p)[0], (p)[1], (p)[2], (p)[3]})

// One SUB4 stage: DS cluster (8 gathers + 7 coefs + next bases) then FMA
// cluster, SB-pinned at the stage boundary to bound live ranges.
#define STAGE(S, LASTQ, FOLD_DS, FOLD_FMA)                                    \
    vf4 t4_##S;                                                               \
    {                                                                         \
        const float *pa0 = &xs[cb0.x + off], *pb0 = &xs[cb0.y + off];         \
        const float *pa1 = &xs[cb1.x + off], *pb1 = &xs[cb1.y + off];         \
        const float *pa2 = &xs[cb2.x + off], *pb2 = &xs[cb2.y + off];         \
        const float *pa3 = &xs[cb3.x + off], *pb3 = &xs[cb3.y + off];         \
        const vf4 A0 = LD4(pa0), B0 = LD4(pb0);                               \
        const vf4 A1 = LD4(pa1), B1 = LD4(pb1);                               \
        const vf4 A2 = LD4(pa2), B2 = LD4(pb2);                               \
        const vf4 A3 = LD4(pa3), B3 = LD4(pb3);                               \
        const vf4 c0 = coefs[4*S], c1 = coefs[4*S+1];                         \
        const vf4 c2 = coefs[4*S+2], c3 = coefs[4*S+3];                       \
        const vf4 d0 = coefs[32+2*S], d1 = coefs[33+2*S], e0 = coefs[48+S];   \
        FOLD_DS                                                               \
        if (!(LASTQ)) {                                                       \
            cb0 = bases[4*S+4]; cb1 = bases[4*S+5];                           \
            cb2 = bases[4*S+6]; cb3 = bases[4*S+7];                           \
        }                                                                     \
        const vf4 u0 = comb(A0, B0, c0), u1 = comb(A1, B1, c1);               \
        const vf4 u2 = comb(A2, B2, c2), u3 = comb(A3, B3, c3);               \
        t4_##S = comb(comb(u0, u1, d0), comb(u2, u3, d1), e0);                \
        FOLD_FMA                                                              \
        SB;                                                                   \
    }

__global__ __launch_bounds__(TPB) void logic_conv_kernel(
    const float* __restrict__ x,
    const int*   __restrict__ h_idx,
    const int*   __restrict__ w_idx,
    const int*   __restrict__ c_idx,
    const float* __restrict__ w0, const float* __restrict__ w1,
    const float* __restrict__ w2, const float* __restrict__ w3,
    const float* __restrict__ w4, const float* __restrict__ w5,
    float* __restrict__ out)
{
    __shared__ float xs[Cc * XCH];      // 3*2210*4 = 26,520 B
    __shared__ vf4   coefs[63];
    __shared__ int2  bases[32];

    const int tid  = threadIdx.x;
    const int blk  = blockIdx.x;
    const int b    = blk >> 6;          // 16 images
    const int k    = (blk >> 1) & 31;   // 32 filters
    const int half = blk & 1;           // row-half of the output
    const int oh0  = half * OHSUB;

    // ---- stage rows [oh0, oh0+34) of x[b] into padded LDS ----
    const float* xb = x + b * (Cc * Hh * Ww);
    #pragma unroll
    for (int it = 0; it < 7; ++it) {
        const int flat = it * TPB + tid;           // float4 index, 0..1631
        if (flat < Cc * ROWS * 16) {
            const int c   = flat / (ROWS * 16);
            const int rem = flat - c * (ROWS * 16);
            const int r   = rem >> 4;
            const int w4i = rem & 15;
            const float4 v = *reinterpret_cast<const float4*>(
                xb + c * (Hh * Ww) + (oh0 + r) * Ww + (w4i << 2));
            float* d = &xs[c * XCH + r * XROW + (w4i << 2)];
            d[0] = v.x; d[1] = v.y; d[2] = v.z; d[3] = v.w;
        }
    }

    // ---- gather bases: LDS offsets for each leaf's two inputs ----
    if (tid < 32) {
        const int i0 = (0 * Kk + k) * Ss + tid;
        const int i1 = (1 * Kk + k) * Ss + tid;
        bases[tid] = make_int2(
            c_idx[i0] * XCH + h_idx[i0] * XROW + w_idx[i0],
            c_idx[i1] * XCH + h_idx[i1] * XROW + w_idx[i1]);
    }

    // ---- per-node coefficients: softmax(w)/LUT folded to 4 floats ----
    if (tid >= 64 && tid < 127) {
        const int t = tid - 64;
        const float* wp; int n;
        if      (t < 32) { wp = w0; n = t;      }
        else if (t < 48) { wp = w1; n = t - 32; }
        else if (t < 56) { wp = w2; n = t - 48; }
        else if (t < 60) { wp = w3; n = t - 56; }
        else if (t < 62) { wp = w4; n = t - 60; }
        else             { wp = w5; n = 0;      }
        const float* lg = wp + (n * Kk + k) * 16;
        float l[16];
        float m = lg[0];
        #pragma unroll
        for (int q = 0; q < 16; ++q) { l[q] = lg[q]; m = fmaxf(m, l[q]); }
        float e[16], s = 0.f;
        #pragma unroll
        for (int q = 0; q < 16; ++q) { e[q] = __expf(l[q] - m); s += e[q]; }
        const float inv = 1.f / s;
        float c0 = 0.f, c1 = 0.f, c2 = 0.f, c3 = 0.f;
        #pragma unroll
        for (int op = 0; op < 16; ++op) {
            if (op & 1) c0 += e[op];
            if (op & 2) c1 += e[op];
            if (op & 4) c2 += e[op];
            if (op & 8) c3 += e[op];
        }
        c0 *= inv; c1 *= inv; c2 *= inv; c3 *= inv;
        coefs[t] = (vf4){c0, c2 - c0, c1 - c0, c0 - c1 - c2 + c3};
    }

    __syncthreads();

    // ---- main loop: oh-major (lane row-stride 1 -> conflict-free LDS reads) ----
    float* outp = out + (b * Kk + k) * Pp + oh0 * OWw;
    #pragma unroll 1
    for (int it = 0; it < 2; ++it) {
        const int g = it * TPB + tid;
        if (g < NGRP) {
            const int oh  = g % OHSUB;          // consecutive lanes -> consecutive rows
            const int ow0 = (g / OHSUB) << 2;
            const int off = oh * XROW + ow0;

            int2 cb0 = bases[0], cb1 = bases[1], cb2 = bases[2], cb3 = bases[3];
            vf4 t8a, t8b, t16a, t16b, y;

            STAGE(0, 0, , )
            STAGE(1, 0,
                  const vf4 f0 = coefs[56];,
                  t8a = comb(t4_0, t4_1, f0);)
            STAGE(2, 0, , )
            STAGE(3, 0,
                  const vf4 f1 = coefs[57]; const vf4 g0 = coefs[60];,
                  t8b = comb(t4_2, t4_3, f1); t16a = comb(t8a, t8b, g0);)
            STAGE(4, 0, , )
            STAGE(5, 0,
                  const vf4 f2 = coefs[58];,
                  t8a = comb(t4_4, t4_5, f2);)
            STAGE(6, 0, , )
            STAGE(7, 1,
                  const vf4 f3 = coefs[59]; const vf4 g1 = coefs[61];
                  const vf4 rc = coefs[62];,
                  t8b = comb(t4_6, t4_7, f3); t16b = comb(t8a, t8b, g1);
                  y = comb(t16a, t16b, rc);)

            *reinterpret_cast<vf4*>(outp + oh * OWw + ow0) = y;
        }
    }
}

extern "C" void kernel_launch(void* const* d_in, const int* in_sizes, int n_in,
                              void* d_out, int out_size, void* d_ws, size_t ws_size,
                              hipStream_t stream) {
    const float* x     = (const float*)d_in[0];
    const int*   h_idx = (const int*)d_in[1];
    const int*   w_idx = (const int*)d_in[2];
    const int*   c_idx = (const int*)d_in[3];
    const float* w0    = (const float*)d_in[4];
    const float* w1    = (const float*)d_in[5];
    const float* w2    = (const float*)d_in[6];
    const float* w3    = (const float*)d_in[7];
    const float* w4    = (const float*)d_in[8];
    const float* w5    = (const float*)d_in[9];
    float* out = (float*)d_out;

    dim3 grid(Bb * Kk * 2);   // 1024 blocks: (b, k, row-half)
    dim3 block(TPB);
    hipLaunchKernelGGL(logic_conv_kernel, grid, block, 0, stream,
                       x, h_idx, w_idx, c_idx, w0, w1, w2, w3, w4, w5, out);
}

// Round 7
// 22.229 us; speedup vs baseline: 22.2363x; 1.2232x over previous
//
#include <hip/hip_runtime.h>
#include <hip/hip_fp16.h>
#include <math.h>

// Problem constants (match reference)
#define Bb   16
#define Cc   3
#define Hh   64
#define Ww   64
#define Kk   32
#define Ss   32
#define OHh  60
#define OWw  60
#define Pp   3600
#define ROWS 34            // staged rows per block: 30 output rows + R-1
#define OHSUB 30
#define NGRP 450           // 30 rows * 15 groups of 4 columns
#define TPB  256

// fp16 LDS layout (dword units): row = 33 dwords (66 halfs: 64 data + pad).
// Bank stride per row = 33 mod 32 = 1 -> oh-major lanes are conflict-free.
// Two copies: S0[p] = x[p], S1[p] = x[p+1]; a leaf at col w reads
// copy (w&1) starting at half (w - (w&1)) -> every gather is one aligned
// dword pair (ds_read2_b32), 4 px per 8 bytes.
#define DWROW  33
#define DWC    (ROWS * DWROW)   // 1122 dwords per channel
#define DWCOPY (Cc * DWC)       // 3366 dwords per copy

typedef float vf4 __attribute__((ext_vector_type(4)));
typedef float vf4u __attribute__((ext_vector_type(4), aligned(4)));

#define SB __builtin_amdgcn_sched_barrier(0)

static __device__ __forceinline__ vf4 vsplat(float s) { return (vf4){s, s, s, s}; }

// combine: y = c0 + a*dA + b*dB + a*b*dAB  (c = {c0, dA, dB, dAB})
static __device__ __forceinline__ vf4 comb(vf4 a, vf4 b, vf4 c) {
    const vf4 t = __builtin_elementwise_fma(b, vsplat(c.w), vsplat(c.y));
    const vf4 u = __builtin_elementwise_fma(b, vsplat(c.z), vsplat(c.x));
    return __builtin_elementwise_fma(a, t, u);
}

// pack two f32 -> one dword of two f16 (RTE)
static __device__ __forceinline__ unsigned int pkh(float lo, float hi) {
    __half2 h = __floats2half2_rn(lo, hi);
    return *reinterpret_cast<unsigned int*>(&h);
}

// gather 4 consecutive px worth of one leaf-input: one dword pair from LDS
#define GATH(dbase, dst)                                                     \
    {                                                                        \
        const unsigned int lo = xsh[(dbase) + loff];                         \
        const unsigned int hi = xsh[(dbase) + loff + 1];                     \
        const __half2 hl = *reinterpret_cast<const __half2*>(&lo);           \
        const __half2 hh = *reinterpret_cast<const __half2*>(&hi);           \
        const float2 fl = __half22float2(hl);                                \
        const float2 fh = __half22float2(hh);                                \
        dst = (vf4){fl.x, fl.y, fh.x, fh.y};                                 \
    }

// One SUB4 stage: DS cluster (8 gathers + 7 coefs + next bases) then FMA
// cluster, SB-pinned at the stage boundary to bound live ranges (no spill).
#define STAGE(S, LASTQ, FOLD_DS, FOLD_FMA)                                    \
    vf4 t4_##S;                                                               \
    {                                                                         \
        vf4 A0, B0, A1, B1, A2, B2, A3, B3;                                   \
        GATH(cb0.x, A0); GATH(cb0.y, B0);                                     \
        GATH(cb1.x, A1); GATH(cb1.y, B1);                                     \
        GATH(cb2.x, A2); GATH(cb2.y, B2);                                     \
        GATH(cb3.x, A3); GATH(cb3.y, B3);                                     \
        const vf4 c0 = coefs[4*S], c1 = coefs[4*S+1];                         \
        const vf4 c2 = coefs[4*S+2], c3 = coefs[4*S+3];                       \
        const vf4 d0 = coefs[32+2*S], d1 = coefs[33+2*S], e0 = coefs[48+S];   \
        FOLD_DS                                                               \
        if constexpr (!(LASTQ)) {                                             \
            cb0 = bases[(4*S+4) & 31]; cb1 = bases[(4*S+5) & 31];             \
            cb2 = bases[(4*S+6) & 31]; cb3 = bases[(4*S+7) & 31];             \
        }                                                                     \
        const vf4 u0 = comb(A0, B0, c0), u1 = comb(A1, B1, c1);               \
        const vf4 u2 = comb(A2, B2, c2), u3 = comb(A3, B3, c3);               \
        t4_##S = comb(comb(u0, u1, d0), comb(u2, u3, d1), e0);                \
        FOLD_FMA                                                              \
        SB;                                                                   \
    }

__global__ __launch_bounds__(TPB) void logic_conv_kernel(
    const float* __restrict__ x,
    const int*   __restrict__ h_idx,
    const int*   __restrict__ w_idx,
    const int*   __restrict__ c_idx,
    const float* __restrict__ w0, const float* __restrict__ w1,
    const float* __restrict__ w2, const float* __restrict__ w3,
    const float* __restrict__ w4, const float* __restrict__ w5,
    float* __restrict__ out)
{
    __shared__ unsigned int xsh[2 * DWCOPY];   // 26,928 B
    __shared__ vf4  coefs[63];
    __shared__ int2 bases[32];

    const int tid  = threadIdx.x;
    const int blk  = blockIdx.x;
    const int b    = blk >> 6;          // 16 images
    const int k    = (blk >> 1) & 31;   // 32 filters
    const int half = blk & 1;           // row-half of the output
    const int oh0  = half * OHSUB;

    // ---- stage rows [oh0, oh0+34) of x[b] as fp16, two shifted copies ----
    const float* xb = x + b * (Cc * Hh * Ww);
    #pragma unroll
    for (int it = 0; it < 7; ++it) {
        const int flat = it * TPB + tid;           // chunk of 4 floats, 0..1631
        if (flat < Cc * ROWS * 16) {
            const int c   = flat / (ROWS * 16);    // /544
            const int rem = flat - c * (ROWS * 16);
            const int r   = rem >> 4;
            const int w4i = rem & 15;
            const int w0c = w4i << 2;
            const float* src = xb + c * (Hh * Ww) + (oh0 + r) * Ww + w0c;
            const vf4u A = *reinterpret_cast<const vf4u*>(src);
            vf4u Bv;
            if (w4i < 15) Bv = *reinterpret_cast<const vf4u*>(src + 1);
            else          Bv = (vf4u){A.y, A.z, A.w, A.w};   // tail: pad col never read
            const int di = c * DWC + r * DWROW + (w0c >> 1);
            xsh[di]              = pkh(A.x, A.y);
            xsh[di + 1]          = pkh(A.z, A.w);
            xsh[DWCOPY + di]     = pkh(Bv.x, Bv.y);
            xsh[DWCOPY + di + 1] = pkh(Bv.z, Bv.w);
        }
    }

    // ---- gather bases: dword index of each leaf-input (copy by col parity) ----
    if (tid < 32) {
        const int i0 = (0 * Kk + k) * Ss + tid;
        const int i1 = (1 * Kk + k) * Ss + tid;
        const int wA = w_idx[i0], sA = wA & 1;
        const int wB = w_idx[i1], sB = wB & 1;
        bases[tid] = make_int2(
            sA * DWCOPY + c_idx[i0] * DWC + h_idx[i0] * DWROW + ((wA - sA) >> 1),
            sB * DWCOPY + c_idx[i1] * DWC + h_idx[i1] * DWROW + ((wB - sB) >> 1));
    }

    // ---- per-node coefficients: softmax(w)/LUT folded to 4 floats ----
    if (tid >= 64 && tid < 127) {
        const int t = tid - 64;
        const float* wp; int n;
        if      (t < 32) { wp = w0; n = t;      }
        else if (t < 48) { wp = w1; n = t - 32; }
        else if (t < 56) { wp = w2; n = t - 48; }
        else if (t < 60) { wp = w3; n = t - 56; }
        else if (t < 62) { wp = w4; n = t - 60; }
        else             { wp = w5; n = 0;      }
        const float* lg = wp + (n * Kk + k) * 16;
        float l[16];
        float m = lg[0];
        #pragma unroll
        for (int q = 0; q < 16; ++q) { l[q] = lg[q]; m = fmaxf(m, l[q]); }
        float e[16], s = 0.f;
        #pragma unroll
        for (int q = 0; q < 16; ++q) { e[q] = __expf(l[q] - m); s += e[q]; }
        const float inv = 1.f / s;
        float c0 = 0.f, c1 = 0.f, c2 = 0.f, c3 = 0.f;
        #pragma unroll
        for (int op = 0; op < 16; ++op) {
            if (op & 1) c0 += e[op];
            if (op & 2) c1 += e[op];
            if (op & 4) c2 += e[op];
            if (op & 8) c3 += e[op];
        }
        c0 *= inv; c1 *= inv; c2 *= inv; c3 *= inv;
        coefs[t] = (vf4){c0, c2 - c0, c1 - c0, c0 - c1 - c2 + c3};
    }

    __syncthreads();

    // ---- main loop: oh-major (lane bank stride 1 -> conflict-free) ----
    float* outp = out + (b * Kk + k) * Pp + oh0 * OWw;
    #pragma unroll 1
    for (int it = 0; it < 2; ++it) {
        const int g = it * TPB + tid;
        if (g < NGRP) {
            const int oh   = g % OHSUB;         // consecutive lanes -> consecutive rows
            const int owg  = g / OHSUB;         // 0..14
            const int loff = oh * DWROW + (owg << 1);   // dword offset within copy

            int2 cb0 = bases[0], cb1 = bases[1], cb2 = bases[2], cb3 = bases[3];
            vf4 t8a, t8b, t16a, t16b, y;

            STAGE(0, 0, , )
            STAGE(1, 0,
                  const vf4 f0 = coefs[56];,
                  t8a = comb(t4_0, t4_1, f0);)
            STAGE(2, 0, , )
            STAGE(3, 0,
                  const vf4 f1 = coefs[57]; const vf4 g0 = coefs[60];,
                  t8b = comb(t4_2, t4_3, f1); t16a = comb(t8a, t8b, g0);)
            STAGE(4, 0, , )
            STAGE(5, 0,
                  const vf4 f2 = coefs[58];,
                  t8a = comb(t4_4, t4_5, f2);)
            STAGE(6, 0, , )
            STAGE(7, 1,
                  const vf4 f3 = coefs[59]; const vf4 g1 = coefs[61];
                  const vf4 rc = coefs[62];,
                  t8b = comb(t4_6, t4_7, f3); t16b = comb(t8a, t8b, g1);
                  y = comb(t16a, t16b, rc);)

            *reinterpret_cast<vf4*>(outp + oh * OWw + (owg << 2)) = y;
        }
    }
}

extern "C" void kernel_launch(void* const* d_in, const int* in_sizes, int n_in,
                              void* d_out, int out_size, void* d_ws, size_t ws_size,
                              hipStream_t stream) {
    const float* x     = (const float*)d_in[0];
    const int*   h_idx = (const int*)d_in[1];
    const int*   w_idx = (const int*)d_in[2];
    const int*   c_idx = (const int*)d_in[3];
    const float* w0    = (const float*)d_in[4];
    const float* w1    = (const float*)d_in[5];
    const float* w2    = (const float*)d_in[6];
    const float* w3    = (const float*)d_in[7];
    const float* w4    = (const float*)d_in[8];
    const float* w5    = (const float*)d_in[9];
    float* out = (float*)d_out;

    dim3 grid(Bb * Kk * 2);   // 1024 blocks: (b, k, row-half)
    dim3 block(TPB);
    hipLaunchKernelGGL(logic_conv_kernel, grid, block, 0, stream,
                       x, h_idx, w_idx, c_idx, w0, w1, w2, w3, w4, w5, out);
}